// Round 9
// baseline (52.836 us; speedup 1.0000x reference)
//
#include <hip/hip_runtime.h>

// G=16, H=8, N=128/side, HD=32, D=256
// x tensors: plain row-major [2048][256] f32; head (g,h) chunk = rows g*128+h*16..+16,
// viewed flat as [128 nodes][32]. chunk base float offset = gh*4096.
#define C2L2E 2.8853900817779268f   // 2*log2(e)
#define LOG2E 1.4426950408889634f

// ws float offsets
#define WS_X1   0          // [2048][256] f32 x1
#define WS_X2   524288     // [2048][256] f32 x2
// bf16 hi/lo staging in MFMA-fragment order [tile][kt][lane][8] (ushort arrays)
#define WS_AH   1048576
#define WS_AL   1310720
#define WS_BH   1572864
#define WS_BL   1835008
#define WS_W1H  2097152
#define WS_W1L  2129920
#define WS_W2H  2162688
#define WS_W2L  2195456

// k23 LDS float offsets
#define L_X2    0          // 128*32 swizzled
#define L_X1    4096       // 128*32 swizzled
#define L_SMAT  8192       // 128*132
#define L_COLP  25088      // 16*128
#define L_RED8  27136      // 128*8
#define L_RSUM  28160      // 128
#define L_CSUM  28288      // 128
#define L_WARR  28416      // 2*128
#define L_REDM  28672      // 8
#define L_PART  28680      // 2*4*32
// total 28936 floats = 115.7 KiB

typedef short bf16x8 __attribute__((ext_vector_type(8)));
typedef float f32x4 __attribute__((ext_vector_type(4)));

__device__ __forceinline__ int swz4(int row, int c4) { return (c4 ^ (row & 7)) << 2; }
__device__ __forceinline__ int swzf(int row, int k) {
    return (((k >> 2) ^ (row & 7)) << 2) | (k & 3);
}

__device__ __forceinline__ unsigned short bf16rne(float f) {
    unsigned u = __float_as_uint(f);
    u += 0x7FFF + ((u >> 16) & 1);
    return (unsigned short)(u >> 16);
}
__device__ __forceinline__ float bf16tof(unsigned short h) {
    return __uint_as_float(((unsigned)h) << 16);
}

// ================= K0: fp32 -> bf16 hi/lo split, MFMA-fragment layout =================
// One thread per 8-elem fragment: elem (tile rt|ct, kt, lane, e) = Src[rt*16+(lane&15)][kt*32+(lane>>4)*8+e].
// Dst ushort index = t_local*8 + e  (fragment-contiguous -> k1 loads are lane-coalesced 16B).
// A: 65536 frags, B: 65536, W1: 8192, W2: 8192 -> 147456 threads = 576 x 256.
__global__ __launch_bounds__(256) void k0_convert(
        const float* __restrict__ A, const float* __restrict__ B,
        const float* __restrict__ W1, const float* __restrict__ W2,
        float* __restrict__ ws) {
    const int t = blockIdx.x * 256 + threadIdx.x;
    const float* src; unsigned short *dh, *dl; int tl;
    if (t < 65536)       { src = A;  dh = (unsigned short*)(ws + WS_AH);  dl = (unsigned short*)(ws + WS_AL);  tl = t; }
    else if (t < 131072) { src = B;  dh = (unsigned short*)(ws + WS_BH);  dl = (unsigned short*)(ws + WS_BL);  tl = t - 65536; }
    else if (t < 139264) { src = W1; dh = (unsigned short*)(ws + WS_W1H); dl = (unsigned short*)(ws + WS_W1L); tl = t - 131072; }
    else                 { src = W2; dh = (unsigned short*)(ws + WS_W2H); dl = (unsigned short*)(ws + WS_W2L); tl = t - 139264; }
    const int lane = tl & 63, kt = (tl >> 6) & 7, rt = tl >> 9;
    const int row = rt * 16 + (lane & 15);
    const int col = kt * 32 + (lane >> 4) * 8;
    float4 v0 = *(const float4*)(src + (size_t)row * 256 + col);
    float4 v1 = *(const float4*)(src + (size_t)row * 256 + col + 4);
    ushort4 h0, h1, l0, l1;
    h0.x = bf16rne(v0.x); l0.x = bf16rne(v0.x - bf16tof(h0.x));
    h0.y = bf16rne(v0.y); l0.y = bf16rne(v0.y - bf16tof(h0.y));
    h0.z = bf16rne(v0.z); l0.z = bf16rne(v0.z - bf16tof(h0.z));
    h0.w = bf16rne(v0.w); l0.w = bf16rne(v0.w - bf16tof(h0.w));
    h1.x = bf16rne(v1.x); l1.x = bf16rne(v1.x - bf16tof(h1.x));
    h1.y = bf16rne(v1.y); l1.y = bf16rne(v1.y - bf16tof(h1.y));
    h1.z = bf16rne(v1.z); l1.z = bf16rne(v1.z - bf16tof(h1.z));
    h1.w = bf16rne(v1.w); l1.w = bf16rne(v1.w - bf16tof(h1.w));
    ((ushort4*)dh)[tl * 2]     = h0;
    ((ushort4*)dh)[tl * 2 + 1] = h1;
    ((ushort4*)dl)[tl * 2]     = l0;
    ((ushort4*)dl)[tl * 2 + 1] = l1;
}

// ================= K1: split-bf16 MFMA GEMM x = In @ W^T + bias =================
// grid 256: mat=bid>>7; idx=bid&127 -> r0=(idx>>2)*64, c0=(idx&3)*64. 4 waves, wave=16-row tile.
// All fragment loads lane-coalesced (16B/lane) from k0's layout. Epilogue mapping verified (r8).
__global__ __launch_bounds__(256) void k1_mfma(
        const float* __restrict__ b1, const float* __restrict__ b2,
        float* __restrict__ ws) {
    const int bid = blockIdx.x, tid = threadIdx.x;
    const int mat = bid >> 7, idx = bid & 127;
    const int r0 = (idx >> 2) * 64, c0 = (idx & 3) * 64;
    const unsigned short* IH = (const unsigned short*)(ws + (mat ? WS_BH : WS_AH));
    const unsigned short* IL = (const unsigned short*)(ws + (mat ? WS_BL : WS_AL));
    const unsigned short* WHp = (const unsigned short*)(ws + (mat ? WS_W2H : WS_W1H));
    const unsigned short* WLp = (const unsigned short*)(ws + (mat ? WS_W2L : WS_W1L));
    const float* bs = mat ? b2 : b1;
    float* xo = ws + (mat ? WS_X2 : WS_X1);

    const int wv = tid >> 6, lane = tid & 63;
    const int rt = (idx >> 2) * 4 + wv;         // 16-row tile index
    const int ct0 = (idx & 3) * 4;              // first 16-col tile

    f32x4 acc[4];
    #pragma unroll
    for (int nt = 0; nt < 4; ++nt) acc[nt] = (f32x4){0.f, 0.f, 0.f, 0.f};

    for (int kt = 0; kt < 8; ++kt) {
        bf16x8 ah = *(const bf16x8*)(IH + ((size_t)(rt * 8 + kt) * 64 + lane) * 8);
        bf16x8 al = *(const bf16x8*)(IL + ((size_t)(rt * 8 + kt) * 64 + lane) * 8);
        #pragma unroll
        for (int nt = 0; nt < 4; ++nt) {
            const int ct = ct0 + nt;
            bf16x8 wh = *(const bf16x8*)(WHp + ((size_t)(ct * 8 + kt) * 64 + lane) * 8);
            bf16x8 wl = *(const bf16x8*)(WLp + ((size_t)(ct * 8 + kt) * 64 + lane) * 8);
            acc[nt] = __builtin_amdgcn_mfma_f32_16x16x32_bf16(ah, wh, acc[nt], 0, 0, 0);
            acc[nt] = __builtin_amdgcn_mfma_f32_16x16x32_bf16(ah, wl, acc[nt], 0, 0, 0);
            acc[nt] = __builtin_amdgcn_mfma_f32_16x16x32_bf16(al, wh, acc[nt], 0, 0, 0);
        }
    }

    const int rowb = r0 + wv * 16 + (lane >> 4) * 4;   // C/D: row=(lane>>4)*4+reg, col=lane&15
    const int l16 = lane & 15;
    #pragma unroll
    for (int nt = 0; nt < 4; ++nt) {
        const int col = c0 + nt * 16 + l16;
        const float bb = bs[col];
        #pragma unroll
        for (int rg = 0; rg < 4; ++rg)
            xo[(size_t)(rowb + rg) * 256 + col] = acc[nt][rg] + bb;
    }
}

// ================= K23: fused tanh-att + softmax + weighted sums =================
// grid 128 (one block per gh), 1024 threads (16 waves). No cross-block deps.
// jp=tid&63 -> j in {jp, jp+64}; iset=tid>>6 -> rows iset*8..+8.
__global__ __launch_bounds__(1024) void k23_att_finish(
        float* __restrict__ ws, const float* __restrict__ q,
        float* __restrict__ out) {
    __shared__ float sm[28936];
    const int tid = threadIdx.x;
    const int gh = blockIdx.x;
    const int g = gh >> 3, h = gh & 7;
    float* x2L = sm + L_X2;
    float* x1L = sm + L_X1;

    // stage x1/x2 full chunks (128x32 each), swizzled
    {
        const float4* src2 = (const float4*)(ws + WS_X2 + (size_t)gh * 4096);
        const float4* src1 = (const float4*)(ws + WS_X1 + (size_t)gh * 4096);
        float4 v = src2[tid];
        float4 w = src1[tid];
        const int ni = tid >> 3, c4 = tid & 7;
        *(float4*)(x2L + ni * 32 + swz4(ni, c4)) = v;
        *(float4*)(x1L + ni * 32 + swz4(ni, c4)) = w;
    }
    __syncthreads();

    // att: S(i,j) = sum_k (-2 q_k)/(exp2(2log2e*x1*x2)+1); uniform Qsum shift dropped
    {
        const int jp = tid & 63, iset = tid >> 6;
        float xr0[32], xr1[32], qt[32];
        #pragma unroll
        for (int cc = 0; cc < 8; ++cc) {
            float4 v = *(float4*)(x2L + jp * 32 + swz4(jp, cc));
            xr0[cc*4+0] = v.x * C2L2E; xr0[cc*4+1] = v.y * C2L2E;
            xr0[cc*4+2] = v.z * C2L2E; xr0[cc*4+3] = v.w * C2L2E;
            float4 w = *(float4*)(x2L + (jp + 64) * 32 + swz4(jp + 64, cc));
            xr1[cc*4+0] = w.x * C2L2E; xr1[cc*4+1] = w.y * C2L2E;
            xr1[cc*4+2] = w.z * C2L2E; xr1[cc*4+3] = w.w * C2L2E;
            float4 qv = *(const float4*)(q + cc * 4);   // uniform -> s_load
            qt[cc*4+0] = -2.f * qv.x; qt[cc*4+1] = -2.f * qv.y;
            qt[cc*4+2] = -2.f * qv.z; qt[cc*4+3] = -2.f * qv.w;
        }
        float colacc0 = 0.f, colacc1 = 0.f;
        for (int rr = 0; rr < 8; ++rr) {
            const int r = iset * 8 + rr;
            float Sa = 0.f, Sb = 0.f;
            #pragma unroll
            for (int cc = 0; cc < 8; ++cc) {
                float4 a4 = *(float4*)(x1L + r * 32 + swz4(r, cc));   // broadcast
                // j = jp
                {
                    float p0 = a4.x * xr0[cc*4+0], p1 = a4.y * xr0[cc*4+1];
                    float d0 = __builtin_amdgcn_exp2f(fminf(p0, 60.f)) + 1.f;
                    float d1 = __builtin_amdgcn_exp2f(fminf(p1, 60.f)) + 1.f;
                    float rD = __builtin_amdgcn_rcpf(d0 * d1);
                    float U  = fmaf(qt[cc*4+1], d0, qt[cc*4+0] * d1);
                    Sa = fmaf(U, rD, Sa);
                    p0 = a4.z * xr0[cc*4+2]; p1 = a4.w * xr0[cc*4+3];
                    d0 = __builtin_amdgcn_exp2f(fminf(p0, 60.f)) + 1.f;
                    d1 = __builtin_amdgcn_exp2f(fminf(p1, 60.f)) + 1.f;
                    rD = __builtin_amdgcn_rcpf(d0 * d1);
                    U  = fmaf(qt[cc*4+3], d0, qt[cc*4+2] * d1);
                    Sa = fmaf(U, rD, Sa);
                }
                // j = jp + 64
                {
                    float p0 = a4.x * xr1[cc*4+0], p1 = a4.y * xr1[cc*4+1];
                    float d0 = __builtin_amdgcn_exp2f(fminf(p0, 60.f)) + 1.f;
                    float d1 = __builtin_amdgcn_exp2f(fminf(p1, 60.f)) + 1.f;
                    float rD = __builtin_amdgcn_rcpf(d0 * d1);
                    float U  = fmaf(qt[cc*4+1], d0, qt[cc*4+0] * d1);
                    Sb = fmaf(U, rD, Sb);
                    p0 = a4.z * xr1[cc*4+2]; p1 = a4.w * xr1[cc*4+3];
                    d0 = __builtin_amdgcn_exp2f(fminf(p0, 60.f)) + 1.f;
                    d1 = __builtin_amdgcn_exp2f(fminf(p1, 60.f)) + 1.f;
                    rD = __builtin_amdgcn_rcpf(d0 * d1);
                    U  = fmaf(qt[cc*4+3], d0, qt[cc*4+2] * d1);
                    Sb = fmaf(U, rD, Sb);
                }
            }
            sm[L_SMAT + r * 132 + jp]      = Sa;
            sm[L_SMAT + r * 132 + jp + 64] = Sb;
            colacc0 += Sa; colacc1 += Sb;
        }
        sm[L_COLP + iset * 128 + jp]      = colacc0;
        sm[L_COLP + iset * 128 + jp + 64] = colacc1;
    }
    __syncthreads();

    // rowsum stage 1
    {
        const int row = tid >> 3, seg = tid & 7;
        float acc = 0.f;
        #pragma unroll
        for (int m = 0; m < 4; ++m) {
            float4 v = *(float4*)(sm + L_SMAT + row * 132 + seg * 16 + m * 4);
            acc += (v.x + v.y) + (v.z + v.w);
        }
        sm[L_RED8 + row * 8 + seg] = acc;
    }
    __syncthreads();
    if (tid < 128) {
        float s = 0.f;
        #pragma unroll
        for (int m = 0; m < 8; ++m) s += sm[L_RED8 + tid * 8 + m];
        sm[L_RSUM + tid] = s;
        float cs = 0.f;
        #pragma unroll
        for (int is = 0; is < 16; ++is) cs += sm[L_COLP + is * 128 + tid];
        sm[L_CSUM + tid] = cs;
    }
    __syncthreads();

    // softmaxes (verified k3 logic, sources from LDS)
    const int side = tid >> 7, u = tid & 127;
    const int w2b = (u >> 6) & 1, lane = tid & 63;
    float m = 0.f, e = 0.f;
    if (tid < 256) {
        m = (side ? sm[L_CSUM + u] : sm[L_RSUM + u]) * 0.0078125f;
        float mx = m;
        #pragma unroll
        for (int d = 32; d >= 1; d >>= 1) mx = fmaxf(mx, __shfl_xor(mx, d));
        if (lane == 0) sm[L_REDM + side * 2 + w2b] = mx;
    }
    __syncthreads();
    if (tid < 256) {
        float mx = fmaxf(sm[L_REDM + side * 2], sm[L_REDM + side * 2 + 1]);
        e = __builtin_amdgcn_exp2f((m - mx) * LOG2E);
        float sme = e;
        #pragma unroll
        for (int d = 32; d >= 1; d >>= 1) sme += __shfl_xor(sme, d);
        if (lane == 0) sm[L_REDM + 4 + side * 2 + w2b] = sme;
    }
    __syncthreads();
    if (tid < 256) {
        float tot = sm[L_REDM + 4 + side * 2] + sm[L_REDM + 4 + side * 2 + 1];
        sm[L_WARR + side * 128 + u] = e * __builtin_amdgcn_rcpf(tot);
    }
    __syncthreads();

    // weighted sums from LDS tiles
    if (tid < 256) {
        const int k = u & 31, is = u >> 5;
        const float* xt = side ? x2L : x1L;
        float p = 0.f;
        #pragma unroll 4
        for (int r2 = 0; r2 < 32; ++r2) {
            const int ni = is * 32 + r2;
            p = fmaf(xt[ni * 32 + swzf(ni, k)], sm[L_WARR + side * 128 + ni], p);
        }
        sm[L_PART + side * 128 + is * 32 + k] = p;
    }
    __syncthreads();
    if (tid < 32) {
        float o = sm[L_PART + tid] + sm[L_PART + 32 + tid]
                + sm[L_PART + 64 + tid] + sm[L_PART + 96 + tid];
        out[(size_t)g * 512 + h * 32 + tid] = o;
    } else if (tid >= 64 && tid < 96) {
        const int kk = tid - 64;
        float o = sm[L_PART + 128 + kk] + sm[L_PART + 160 + kk]
                + sm[L_PART + 192 + kk] + sm[L_PART + 224 + kk];
        out[(size_t)g * 512 + 256 + h * 32 + kk] = o;
    }
}

extern "C" void kernel_launch(void* const* d_in, const int* in_sizes, int n_in,
                              void* d_out, int out_size, void* d_ws, size_t ws_size,
                              hipStream_t stream) {
    const float* A  = (const float*)d_in[0];
    const float* B  = (const float*)d_in[2];
    const float* W1 = (const float*)d_in[4];
    const float* b1 = (const float*)d_in[5];
    const float* W2 = (const float*)d_in[6];
    const float* b2 = (const float*)d_in[7];
    const float* q  = (const float*)d_in[8];
    float* ws  = (float*)d_ws;
    float* out = (float*)d_out;

    k0_convert<<<576, 256, 0, stream>>>(A, B, W1, W2, ws);
    k1_mfma<<<256, 256, 0, stream>>>(b1, b2, ws);
    k23_att_finish<<<128, 1024, 0, stream>>>(ws, q, out);
}

// Round 10
// 43.982 us; speedup vs baseline: 1.2013x; 1.2013x over previous
//
#include <hip/hip_runtime.h>

// G=16, H=8, N=128/side, HD=32, D=256
// x tensors: row-major [2048][256] f32; head (g,h) chunk = flat gh*4096, node-major [128][32].
#define C2L2E 2.8853900817779268f   // 2*log2(e)
#define LOG2E 1.4426950408889634f

// ws float offsets
#define WS_X1   0          // [2048][256] f32 x1 (raw)
#define WS_X2   524288     // [2048][256] f32 x2
#define WS_X1S  1048576    // [2048][256] f32 x1 * 2log2e
#define WS_RS   1572864    // [gh][128] row sums
#define WS_CQ   1589248    // [gh*4+qd][128] col quarter partials
// bf16 hi/lo staging in MFMA-fragment order [tile][kt][lane][8] (ushort arrays)
#define WS_AH   1703936
#define WS_AL   1966080
#define WS_BH   2228224
#define WS_BL   2490368
#define WS_W1H  2752512
#define WS_W1L  2785280
#define WS_W2H  2818048
#define WS_W2L  2850816

typedef short bf16x8 __attribute__((ext_vector_type(8)));
typedef float f32x4 __attribute__((ext_vector_type(4)));

__device__ __forceinline__ unsigned short bf16rne(float f) {
    unsigned u = __float_as_uint(f);
    u += 0x7FFF + ((u >> 16) & 1);
    return (unsigned short)(u >> 16);
}
__device__ __forceinline__ float bf16tof(unsigned short h) {
    return __uint_as_float(((unsigned)h) << 16);
}

// ================= K0: fp32 -> bf16 hi/lo split, MFMA-fragment layout =================
// One thread per 8-elem fragment: elem (tile rt|ct, kt, lane, e) = Src[rt*16+(lane&15)][kt*32+(lane>>4)*8+e].
__global__ __launch_bounds__(256) void k0_convert(
        const float* __restrict__ A, const float* __restrict__ B,
        const float* __restrict__ W1, const float* __restrict__ W2,
        float* __restrict__ ws) {
    const int t = blockIdx.x * 256 + threadIdx.x;
    const float* src; unsigned short *dh, *dl; int tl;
    if (t < 65536)       { src = A;  dh = (unsigned short*)(ws + WS_AH);  dl = (unsigned short*)(ws + WS_AL);  tl = t; }
    else if (t < 131072) { src = B;  dh = (unsigned short*)(ws + WS_BH);  dl = (unsigned short*)(ws + WS_BL);  tl = t - 65536; }
    else if (t < 139264) { src = W1; dh = (unsigned short*)(ws + WS_W1H); dl = (unsigned short*)(ws + WS_W1L); tl = t - 131072; }
    else                 { src = W2; dh = (unsigned short*)(ws + WS_W2H); dl = (unsigned short*)(ws + WS_W2L); tl = t - 139264; }
    const int lane = tl & 63, kt = (tl >> 6) & 7, rt = tl >> 9;
    const int row = rt * 16 + (lane & 15);
    const int col = kt * 32 + (lane >> 4) * 8;
    float4 v0 = *(const float4*)(src + (size_t)row * 256 + col);
    float4 v1 = *(const float4*)(src + (size_t)row * 256 + col + 4);
    ushort4 h0, h1, l0, l1;
    h0.x = bf16rne(v0.x); l0.x = bf16rne(v0.x - bf16tof(h0.x));
    h0.y = bf16rne(v0.y); l0.y = bf16rne(v0.y - bf16tof(h0.y));
    h0.z = bf16rne(v0.z); l0.z = bf16rne(v0.z - bf16tof(h0.z));
    h0.w = bf16rne(v0.w); l0.w = bf16rne(v0.w - bf16tof(h0.w));
    h1.x = bf16rne(v1.x); l1.x = bf16rne(v1.x - bf16tof(h1.x));
    h1.y = bf16rne(v1.y); l1.y = bf16rne(v1.y - bf16tof(h1.y));
    h1.z = bf16rne(v1.z); l1.z = bf16rne(v1.z - bf16tof(h1.z));
    h1.w = bf16rne(v1.w); l1.w = bf16rne(v1.w - bf16tof(h1.w));
    ((ushort4*)dh)[tl * 2]     = h0;
    ((ushort4*)dh)[tl * 2 + 1] = h1;
    ((ushort4*)dl)[tl * 2]     = l0;
    ((ushort4*)dl)[tl * 2 + 1] = l1;
}

// ================= K1: split-bf16 MFMA GEMM x = In @ W^T + bias (+x1s) =================
// grid 256: mat=bid>>7; idx=bid&127 -> r0=(idx>>2)*64, c0=(idx&3)*64. 4 waves, wave=16-row tile.
__global__ __launch_bounds__(256) void k1_mfma(
        const float* __restrict__ b1, const float* __restrict__ b2,
        float* __restrict__ ws) {
    const int bid = blockIdx.x, tid = threadIdx.x;
    const int mat = bid >> 7, idx = bid & 127;
    const int r0 = (idx >> 2) * 64, c0 = (idx & 3) * 64;
    const unsigned short* IH  = (const unsigned short*)(ws + (mat ? WS_BH : WS_AH));
    const unsigned short* IL  = (const unsigned short*)(ws + (mat ? WS_BL : WS_AL));
    const unsigned short* WHp = (const unsigned short*)(ws + (mat ? WS_W2H : WS_W1H));
    const unsigned short* WLp = (const unsigned short*)(ws + (mat ? WS_W2L : WS_W1L));
    const float* bs = mat ? b2 : b1;
    float* xo = ws + (mat ? WS_X2 : WS_X1);

    const int wv = tid >> 6, lane = tid & 63;
    const int rt = (idx >> 2) * 4 + wv;
    const int ct0 = (idx & 3) * 4;

    f32x4 acc[4];
    #pragma unroll
    for (int nt = 0; nt < 4; ++nt) acc[nt] = (f32x4){0.f, 0.f, 0.f, 0.f};

    for (int kt = 0; kt < 8; ++kt) {
        bf16x8 ah = *(const bf16x8*)(IH + ((size_t)(rt * 8 + kt) * 64 + lane) * 8);
        bf16x8 al = *(const bf16x8*)(IL + ((size_t)(rt * 8 + kt) * 64 + lane) * 8);
        #pragma unroll
        for (int nt = 0; nt < 4; ++nt) {
            const int ct = ct0 + nt;
            bf16x8 wh = *(const bf16x8*)(WHp + ((size_t)(ct * 8 + kt) * 64 + lane) * 8);
            bf16x8 wl = *(const bf16x8*)(WLp + ((size_t)(ct * 8 + kt) * 64 + lane) * 8);
            acc[nt] = __builtin_amdgcn_mfma_f32_16x16x32_bf16(ah, wh, acc[nt], 0, 0, 0);
            acc[nt] = __builtin_amdgcn_mfma_f32_16x16x32_bf16(ah, wl, acc[nt], 0, 0, 0);
            acc[nt] = __builtin_amdgcn_mfma_f32_16x16x32_bf16(al, wh, acc[nt], 0, 0, 0);
        }
    }

    const int rowb = r0 + wv * 16 + (lane >> 4) * 4;   // C/D: row=(lane>>4)*4+reg, col=lane&15
    const int l16 = lane & 15;
    #pragma unroll
    for (int nt = 0; nt < 4; ++nt) {
        const int col = c0 + nt * 16 + l16;
        const float bb = bs[col];
        #pragma unroll
        for (int rg = 0; rg < 4; ++rg) {
            float v = acc[nt][rg] + bb;
            xo[(size_t)(rowb + rg) * 256 + col] = v;
            if (mat == 0)
                ws[WS_X1S + (size_t)(rowb + rg) * 256 + col] = v * C2L2E;
        }
    }
}

// ================= K2: S-sums of q·tanh(x1*x2) (round-2 kernel, verified) =================
// att(i,j) = Qsum + S(i,j); S = sum_k (-2q_k)/(t+1), t = exp2(2log2e*x1*x2).
// Qsum is a uniform logit shift -> softmax-invariant -> dropped.
// grid 512: block=(gh, quarter of 32 i-rows). 512 threads: j=tid&127, iset=tid>>7.
__global__ __launch_bounds__(512, 4) void k2_att(
        const float* __restrict__ x1v, const float* __restrict__ x2v,
        const float* __restrict__ q,
        float* __restrict__ rowsum, float* __restrict__ colq) {
    const int bid = blockIdx.x;
    const int gh = bid >> 2;
    const int qd = bid & 3;
    const int tid = threadIdx.x;
    const int j = tid & 127;
    const int iset = __builtin_amdgcn_readfirstlane(tid >> 7);  // wave-uniform 0..3

    __shared__ float Smat[32 * 132];
    __shared__ float colp[4][128];
    __shared__ float red8[32][8];

    // x2 row j -> registers (per-lane global loads, one-time)
    float xr[32];
    {
        const float4* xp = (const float4*)(x2v + (size_t)gh * 4096 + (size_t)j * 32);
        #pragma unroll
        for (int k4 = 0; k4 < 8; ++k4) {
            float4 v = xp[k4];
            xr[k4*4+0] = v.x; xr[k4*4+1] = v.y; xr[k4*4+2] = v.z; xr[k4*4+3] = v.w;
        }
    }
    // qt = -2q
    float qt[32];
    #pragma unroll
    for (int k = 0; k < 32; ++k) qt[k] = -2.0f * q[k];

    const float* x1base = x1v + (size_t)gh * 4096 + (size_t)(qd * 32 + iset * 8) * 32;
    float colacc = 0.f;

    for (int r = 0; r < 8; ++r) {
        const float4* ap = (const float4*)(x1base + r * 32);  // uniform -> s_load
        float a[32];
        #pragma unroll
        for (int k4 = 0; k4 < 8; ++k4) {
            float4 v = ap[k4];
            a[k4*4+0] = v.x; a[k4*4+1] = v.y; a[k4*4+2] = v.z; a[k4*4+3] = v.w;
        }
        float S0 = 0.f, S1 = 0.f;
        #pragma unroll
        for (int kp = 0; kp < 16; ++kp) {
            float p0 = a[2*kp]   * xr[2*kp];
            float p1 = a[2*kp+1] * xr[2*kp+1];
            float d0 = __builtin_amdgcn_exp2f(fminf(p0, 60.f)) + 1.f;
            float d1 = __builtin_amdgcn_exp2f(fminf(p1, 60.f)) + 1.f;
            float rD = __builtin_amdgcn_rcpf(d0 * d1);
            float U  = fmaf(qt[2*kp+1], d0, qt[2*kp] * d1);
            if (kp & 1) S1 = fmaf(U, rD, S1); else S0 = fmaf(U, rD, S0);
        }
        float S = S0 + S1;
        colacc += S;
        Smat[(iset * 8 + r) * 132 + j] = S;
    }
    colp[iset][j] = colacc;
    __syncthreads();

    if (tid < 256) {                       // rowsum stage 1: 16-chunk sums
        const int row = tid >> 3, seg = tid & 7;
        const float4* sp = (const float4*)(Smat + row * 132 + seg * 16);
        float4 v0 = sp[0], v1 = sp[1], v2 = sp[2], v3 = sp[3];
        red8[row][seg] = (v0.x+v0.y+v0.z+v0.w) + (v1.x+v1.y+v1.z+v1.w)
                       + (v2.x+v2.y+v2.z+v2.w) + (v3.x+v3.y+v3.z+v3.w);
    }
    __syncthreads();
    if (tid < 32) {
        float s = 0.f;
        #pragma unroll
        for (int m = 0; m < 8; ++m) s += red8[tid][m];
        rowsum[gh * 128 + qd * 32 + tid] = s;
    }
    if (tid < 128) {
        colq[(size_t)bid * 128 + tid] =
            colp[0][tid] + colp[1][tid] + colp[2][tid] + colp[3][tid];
    }
}

// ================= K3: softmaxes + weighted sums -> out (round-2 kernel, verified) =================
// grid 128 (one per gh), 256 threads: side=tid>>7 (0:A,1:B), u=tid&127
__global__ __launch_bounds__(256) void k3_out(
        const float* __restrict__ x1v, const float* __restrict__ x2v,
        const float* __restrict__ rowsum, const float* __restrict__ colq,
        float* __restrict__ out) {
    const int gh = blockIdx.x;
    const int g = gh >> 3, h = gh & 7;
    const int tid = threadIdx.x;
    const int side = tid >> 7;
    const int u = tid & 127;
    const int w2 = (u >> 6) & 1;
    const int lane = tid & 63;

    __shared__ float warr[2][128];
    __shared__ float red[4];
    __shared__ float red2[4];
    __shared__ float part[2][4][32];

    float m;
    if (side == 0) {
        m = rowsum[gh * 128 + u] * 0.0078125f;
    } else {
        m = (colq[(size_t)(gh * 4 + 0) * 128 + u] + colq[(size_t)(gh * 4 + 1) * 128 + u] +
             colq[(size_t)(gh * 4 + 2) * 128 + u] + colq[(size_t)(gh * 4 + 3) * 128 + u]) * 0.0078125f;
    }

    float mx = m;
    #pragma unroll
    for (int s = 32; s >= 1; s >>= 1) mx = fmaxf(mx, __shfl_xor(mx, s));
    if (lane == 0) red[side * 2 + w2] = mx;
    __syncthreads();
    mx = fmaxf(red[side * 2], red[side * 2 + 1]);

    float e = __builtin_amdgcn_exp2f((m - mx) * LOG2E);
    float sm = e;
    #pragma unroll
    for (int s = 32; s >= 1; s >>= 1) sm += __shfl_xor(sm, s);
    if (lane == 0) red2[side * 2 + w2] = sm;
    __syncthreads();
    const float tot = red2[side * 2] + red2[side * 2 + 1];
    warr[side][u] = e * __builtin_amdgcn_rcpf(tot);
    __syncthreads();

    const int k = u & 31, is = u >> 5;
    const float* xt = (side ? x2v : x1v) + (size_t)gh * 4096;
    float p = 0.f;
    #pragma unroll 4
    for (int r = 0; r < 32; ++r)
        p = fmaf(xt[(is * 32 + r) * 32 + k], warr[side][is * 32 + r], p);
    part[side][is][k] = p;
    __syncthreads();
    if (u < 32) {
        float o = part[side][0][u] + part[side][1][u] + part[side][2][u] + part[side][3][u];
        out[(size_t)g * 512 + side * 256 + h * 32 + u] = o;
    }
}

extern "C" void kernel_launch(void* const* d_in, const int* in_sizes, int n_in,
                              void* d_out, int out_size, void* d_ws, size_t ws_size,
                              hipStream_t stream) {
    const float* A  = (const float*)d_in[0];
    const float* B  = (const float*)d_in[2];
    const float* W1 = (const float*)d_in[4];
    const float* b1 = (const float*)d_in[5];
    const float* W2 = (const float*)d_in[6];
    const float* b2 = (const float*)d_in[7];
    const float* q  = (const float*)d_in[8];
    float* ws  = (float*)d_ws;
    float* out = (float*)d_out;

    k0_convert<<<576, 256, 0, stream>>>(A, B, W1, W2, ws);
    k1_mfma<<<256, 256, 0, stream>>>(b1, b2, ws);
    k2_att<<<512, 512, 0, stream>>>(ws + WS_X1S, ws + WS_X2, q, ws + WS_RS, ws + WS_CQ);
    k3_out<<<128, 256, 0, stream>>>(ws + WS_X1, ws + WS_X2, ws + WS_RS, ws + WS_CQ, out);
}

// Round 12
// 43.847 us; speedup vs baseline: 1.2050x; 1.0031x over previous
//
#include <hip/hip_runtime.h>

// G=16, H=8, N=128/side, HD=32, D=256
// x tensors: row-major [2048][256] f32; head (g,h) chunk = flat gh*4096, node-major [128][32].
#define C2L2E 2.8853900817779268f   // 2*log2(e)
#define LOG2E 1.4426950408889634f

// ws float offsets
#define WS_X1   0          // [2048][256] f32 x1 (raw)
#define WS_X2   524288     // [2048][256] f32 x2
#define WS_X1S  1048576    // [2048][256] f32 x1 * 2log2e
#define WS_RS   1572864    // [gh][128] row sums
#define WS_CQ   1589248    // [gh*4+qd][128] col quarter partials
// bf16 hi/lo staging in MFMA-fragment order [tile][kt][lane][8] (ushort arrays)
#define WS_AH   1703936
#define WS_AL   1966080
#define WS_BH   2228224
#define WS_BL   2490368
#define WS_W1H  2752512
#define WS_W1L  2785280
#define WS_W2H  2818048
#define WS_W2L  2850816

typedef short bf16x8 __attribute__((ext_vector_type(8)));
typedef float f32x4 __attribute__((ext_vector_type(4)));

__device__ __forceinline__ unsigned short bf16rne(float f) {
    unsigned u = __float_as_uint(f);
    u += 0x7FFF + ((u >> 16) & 1);
    return (unsigned short)(u >> 16);
}
__device__ __forceinline__ float bf16tof(unsigned short h) {
    return __uint_as_float(((unsigned)h) << 16);
}
// bit-preserving wave-uniform scalar broadcast (readfirstlane is int-typed!)
__device__ __forceinline__ float rfl(float x) {
    return __uint_as_float(__builtin_amdgcn_readfirstlane(__float_as_uint(x)));
}

// ================= K0: fp32 -> bf16 hi/lo split, MFMA-fragment layout (verified) =================
__global__ __launch_bounds__(256) void k0_convert(
        const float* __restrict__ A, const float* __restrict__ B,
        const float* __restrict__ W1, const float* __restrict__ W2,
        float* __restrict__ ws) {
    const int t = blockIdx.x * 256 + threadIdx.x;
    const float* src; unsigned short *dh, *dl; int tl;
    if (t < 65536)       { src = A;  dh = (unsigned short*)(ws + WS_AH);  dl = (unsigned short*)(ws + WS_AL);  tl = t; }
    else if (t < 131072) { src = B;  dh = (unsigned short*)(ws + WS_BH);  dl = (unsigned short*)(ws + WS_BL);  tl = t - 65536; }
    else if (t < 139264) { src = W1; dh = (unsigned short*)(ws + WS_W1H); dl = (unsigned short*)(ws + WS_W1L); tl = t - 131072; }
    else                 { src = W2; dh = (unsigned short*)(ws + WS_W2H); dl = (unsigned short*)(ws + WS_W2L); tl = t - 139264; }
    const int lane = tl & 63, kt = (tl >> 6) & 7, rt = tl >> 9;
    const int row = rt * 16 + (lane & 15);
    const int col = kt * 32 + (lane >> 4) * 8;
    float4 v0 = *(const float4*)(src + (size_t)row * 256 + col);
    float4 v1 = *(const float4*)(src + (size_t)row * 256 + col + 4);
    ushort4 h0, h1, l0, l1;
    h0.x = bf16rne(v0.x); l0.x = bf16rne(v0.x - bf16tof(h0.x));
    h0.y = bf16rne(v0.y); l0.y = bf16rne(v0.y - bf16tof(h0.y));
    h0.z = bf16rne(v0.z); l0.z = bf16rne(v0.z - bf16tof(h0.z));
    h0.w = bf16rne(v0.w); l0.w = bf16rne(v0.w - bf16tof(h0.w));
    h1.x = bf16rne(v1.x); l1.x = bf16rne(v1.x - bf16tof(h1.x));
    h1.y = bf16rne(v1.y); l1.y = bf16rne(v1.y - bf16tof(h1.y));
    h1.z = bf16rne(v1.z); l1.z = bf16rne(v1.z - bf16tof(h1.z));
    h1.w = bf16rne(v1.w); l1.w = bf16rne(v1.w - bf16tof(h1.w));
    ((ushort4*)dh)[tl * 2]     = h0;
    ((ushort4*)dh)[tl * 2 + 1] = h1;
    ((ushort4*)dl)[tl * 2]     = l0;
    ((ushort4*)dl)[tl * 2 + 1] = l1;
}

// ================= K1: split-bf16 MFMA GEMM x = In @ W^T + bias (+x1s) (verified) =================
__global__ __launch_bounds__(256) void k1_mfma(
        const float* __restrict__ b1, const float* __restrict__ b2,
        float* __restrict__ ws) {
    const int bid = blockIdx.x, tid = threadIdx.x;
    const int mat = bid >> 7, idx = bid & 127;
    const int r0 = (idx >> 2) * 64, c0 = (idx & 3) * 64;
    const unsigned short* IH  = (const unsigned short*)(ws + (mat ? WS_BH : WS_AH));
    const unsigned short* IL  = (const unsigned short*)(ws + (mat ? WS_BL : WS_AL));
    const unsigned short* WHp = (const unsigned short*)(ws + (mat ? WS_W2H : WS_W1H));
    const unsigned short* WLp = (const unsigned short*)(ws + (mat ? WS_W2L : WS_W1L));
    const float* bs = mat ? b2 : b1;
    float* xo = ws + (mat ? WS_X2 : WS_X1);

    const int wv = tid >> 6, lane = tid & 63;
    const int rt = (idx >> 2) * 4 + wv;
    const int ct0 = (idx & 3) * 4;

    f32x4 acc[4];
    #pragma unroll
    for (int nt = 0; nt < 4; ++nt) acc[nt] = (f32x4){0.f, 0.f, 0.f, 0.f};

    for (int kt = 0; kt < 8; ++kt) {
        bf16x8 ah = *(const bf16x8*)(IH + ((size_t)(rt * 8 + kt) * 64 + lane) * 8);
        bf16x8 al = *(const bf16x8*)(IL + ((size_t)(rt * 8 + kt) * 64 + lane) * 8);
        #pragma unroll
        for (int nt = 0; nt < 4; ++nt) {
            const int ct = ct0 + nt;
            bf16x8 wh = *(const bf16x8*)(WHp + ((size_t)(ct * 8 + kt) * 64 + lane) * 8);
            bf16x8 wl = *(const bf16x8*)(WLp + ((size_t)(ct * 8 + kt) * 64 + lane) * 8);
            acc[nt] = __builtin_amdgcn_mfma_f32_16x16x32_bf16(ah, wh, acc[nt], 0, 0, 0);
            acc[nt] = __builtin_amdgcn_mfma_f32_16x16x32_bf16(ah, wl, acc[nt], 0, 0, 0);
            acc[nt] = __builtin_amdgcn_mfma_f32_16x16x32_bf16(al, wh, acc[nt], 0, 0, 0);
        }
    }

    const int rowb = r0 + wv * 16 + (lane >> 4) * 4;
    const int l16 = lane & 15;
    #pragma unroll
    for (int nt = 0; nt < 4; ++nt) {
        const int col = c0 + nt * 16 + l16;
        const float bb = bs[col];
        #pragma unroll
        for (int rg = 0; rg < 4; ++rg) {
            float v = acc[nt][rg] + bb;
            xo[(size_t)(rowb + rg) * 256 + col] = v;
            if (mat == 0)
                ws[WS_X1S + (size_t)(rowb + rg) * 256 + col] = v * C2L2E;
        }
    }
}

// ================= K2: S-sums of q·tanh(x1*x2) — SGPR-resident a/qt version =================
// Same math/block-mapping as the verified round-2/10 kernel. a[] (x1 row, wave-uniform) and
// qt[] (q, grid-uniform) are broadcast to SGPRs via BIT-PRESERVING rfl() -> per-thread VGPRs
// drop to ~xr+temps -> ~6 waves/SIMD (was ~3) to hide the exp2/rcp dependency chains.
__global__ __launch_bounds__(512, 6) void k2_att(
        const float* __restrict__ x1v, const float* __restrict__ x2v,
        const float* __restrict__ q,
        float* __restrict__ rowsum, float* __restrict__ colq) {
    const int bid = blockIdx.x;
    const int gh = bid >> 2;
    const int qd = bid & 3;
    const int tid = threadIdx.x;
    const int j = tid & 127;
    const int iset = __builtin_amdgcn_readfirstlane(tid >> 7);  // wave-uniform 0..3 (int: ok)

    __shared__ float Smat[32 * 132];
    __shared__ float colp[4][128];
    __shared__ float red8[32][8];

    // x2 row j -> VGPRs (per-lane)
    float xr[32];
    {
        const float4* xp = (const float4*)(x2v + (size_t)gh * 4096 + (size_t)j * 32);
        #pragma unroll
        for (int k4 = 0; k4 < 8; ++k4) {
            float4 v = xp[k4];
            xr[k4*4+0] = v.x; xr[k4*4+1] = v.y; xr[k4*4+2] = v.z; xr[k4*4+3] = v.w;
        }
    }
    // qt = -2q -> SGPRs (bit-preserving broadcast)
    float qt[32];
    #pragma unroll
    for (int k4 = 0; k4 < 8; ++k4) {
        float4 v = *(const float4*)(q + k4 * 4);
        qt[k4*4+0] = rfl(v.x) * -2.0f;
        qt[k4*4+1] = rfl(v.y) * -2.0f;
        qt[k4*4+2] = rfl(v.z) * -2.0f;
        qt[k4*4+3] = rfl(v.w) * -2.0f;
    }

    const float* x1base = x1v + (size_t)gh * 4096 + (size_t)(qd * 32 + iset * 8) * 32;
    float colacc = 0.f;

    for (int r = 0; r < 8; ++r) {
        float a[32];                                   // wave-uniform -> SGPRs
        #pragma unroll
        for (int k4 = 0; k4 < 8; ++k4) {
            float4 v = *(const float4*)(x1base + r * 32 + k4 * 4);
            a[k4*4+0] = rfl(v.x);
            a[k4*4+1] = rfl(v.y);
            a[k4*4+2] = rfl(v.z);
            a[k4*4+3] = rfl(v.w);
        }
        float S0 = 0.f, S1 = 0.f;
        #pragma unroll
        for (int kp = 0; kp < 16; ++kp) {
            float p0 = a[2*kp]   * xr[2*kp];
            float p1 = a[2*kp+1] * xr[2*kp+1];
            float d0 = __builtin_amdgcn_exp2f(fminf(p0, 60.f)) + 1.f;
            float d1 = __builtin_amdgcn_exp2f(fminf(p1, 60.f)) + 1.f;
            float rD = __builtin_amdgcn_rcpf(d0 * d1);
            float U  = fmaf(qt[2*kp+1], d0, qt[2*kp] * d1);
            if (kp & 1) S1 = fmaf(U, rD, S1); else S0 = fmaf(U, rD, S0);
        }
        float S = S0 + S1;
        colacc += S;
        Smat[(iset * 8 + r) * 132 + j] = S;
    }
    colp[iset][j] = colacc;
    __syncthreads();

    if (tid < 256) {                       // rowsum stage 1: 16-chunk sums
        const int row = tid >> 3, seg = tid & 7;
        const float4* sp = (const float4*)(Smat + row * 132 + seg * 16);
        float4 v0 = sp[0], v1 = sp[1], v2 = sp[2], v3 = sp[3];
        red8[row][seg] = (v0.x+v0.y+v0.z+v0.w) + (v1.x+v1.y+v1.z+v1.w)
                       + (v2.x+v2.y+v2.z+v2.w) + (v3.x+v3.y+v3.z+v3.w);
    }
    __syncthreads();
    if (tid < 32) {
        float s = 0.f;
        #pragma unroll
        for (int m = 0; m < 8; ++m) s += red8[tid][m];
        rowsum[gh * 128 + qd * 32 + tid] = s;
    }
    if (tid < 128) {
        colq[(size_t)bid * 128 + tid] =
            colp[0][tid] + colp[1][tid] + colp[2][tid] + colp[3][tid];
    }
}

// ================= K3: softmaxes + weighted sums -> out (verified) =================
__global__ __launch_bounds__(256) void k3_out(
        const float* __restrict__ x1v, const float* __restrict__ x2v,
        const float* __restrict__ rowsum, const float* __restrict__ colq,
        float* __restrict__ out) {
    const int gh = blockIdx.x;
    const int g = gh >> 3, h = gh & 7;
    const int tid = threadIdx.x;
    const int side = tid >> 7;
    const int u = tid & 127;
    const int w2 = (u >> 6) & 1;
    const int lane = tid & 63;

    __shared__ float warr[2][128];
    __shared__ float red[4];
    __shared__ float red2[4];
    __shared__ float part[2][4][32];

    float m;
    if (side == 0) {
        m = rowsum[gh * 128 + u] * 0.0078125f;
    } else {
        m = (colq[(size_t)(gh * 4 + 0) * 128 + u] + colq[(size_t)(gh * 4 + 1) * 128 + u] +
             colq[(size_t)(gh * 4 + 2) * 128 + u] + colq[(size_t)(gh * 4 + 3) * 128 + u]) * 0.0078125f;
    }

    float mx = m;
    #pragma unroll
    for (int s = 32; s >= 1; s >>= 1) mx = fmaxf(mx, __shfl_xor(mx, s));
    if (lane == 0) red[side * 2 + w2] = mx;
    __syncthreads();
    mx = fmaxf(red[side * 2], red[side * 2 + 1]);

    float e = __builtin_amdgcn_exp2f((m - mx) * LOG2E);
    float sm = e;
    #pragma unroll
    for (int s = 32; s >= 1; s >>= 1) sm += __shfl_xor(sm, s);
    if (lane == 0) red2[side * 2 + w2] = sm;
    __syncthreads();
    const float tot = red2[side * 2] + red2[side * 2 + 1];
    warr[side][u] = e * __builtin_amdgcn_rcpf(tot);
    __syncthreads();

    const int k = u & 31, is = u >> 5;
    const float* xt = (side ? x2v : x1v) + (size_t)gh * 4096;
    float p = 0.f;
    #pragma unroll 4
    for (int r = 0; r < 32; ++r)
        p = fmaf(xt[(is * 32 + r) * 32 + k], warr[side][is * 32 + r], p);
    part[side][is][k] = p;
    __syncthreads();
    if (u < 32) {
        float o = part[side][0][u] + part[side][1][u] + part[side][2][u] + part[side][3][u];
        out[(size_t)g * 512 + side * 256 + h * 32 + u] = o;
    }
}

extern "C" void kernel_launch(void* const* d_in, const int* in_sizes, int n_in,
                              void* d_out, int out_size, void* d_ws, size_t ws_size,
                              hipStream_t stream) {
    const float* A  = (const float*)d_in[0];
    const float* B  = (const float*)d_in[2];
    const float* W1 = (const float*)d_in[4];
    const float* b1 = (const float*)d_in[5];
    const float* W2 = (const float*)d_in[6];
    const float* b2 = (const float*)d_in[7];
    const float* q  = (const float*)d_in[8];
    float* ws  = (float*)d_ws;
    float* out = (float*)d_out;

    k0_convert<<<576, 256, 0, stream>>>(A, B, W1, W2, ws);
    k1_mfma<<<256, 256, 0, stream>>>(b1, b2, ws);
    k2_att<<<512, 512, 0, stream>>>(ws + WS_X1S, ws + WS_X2, q, ws + WS_RS, ws + WS_CQ);
    k3_out<<<128, 256, 0, stream>>>(ws + WS_X1, ws + WS_X2, ws + WS_RS, ws + WS_CQ, out);
}